// Round 9
// baseline (728.339 us; speedup 1.0000x reference)
//
#include <hip/hip_runtime.h>
#include <math.h>

// Problem constants
#define TT    48
#define BB    96
#define DG    192
#define DH    384
#define NSTEP 47     // T-1 scan steps
#define SETI  3      // inner settling iterations
#define NT    512    // threads per block (8 waves = 2/SIMD -> 256-reg budget)
#define NWAVE 8      // 512/64
#define NOW   6      // owner waves (tid < DH)
#define NG    32     // 16-lane groups per block
#define RPG   12     // rows per group (384/32)
#define LWROWS 192   // Wh rows staged in LDS (rows 0..191)
#define LWSTR  97    // uint2 stride per staged row (96 + 1 pad)
#define PREPNT 768   // prep kernel block size

typedef unsigned short ushort_t;
typedef float f32x2 __attribute__((ext_vector_type(2)));

// ---------- DPP-based reductions (VALU latency, not LDS latency) ----------
template <int CTRL, int RM>
__device__ __forceinline__ float dppadd(float acc, float x) {
  int t = __builtin_amdgcn_update_dpp(0, __float_as_int(x), CTRL, RM, 0xF, false);
  return acc + __int_as_float(t);
}

// Sum of 16 lanes within each row; every lane of the row gets the total.
__device__ __forceinline__ float row16_sum(float v) {
  v = dppadd<0x128, 0xF>(v, v);  // row_ror:8
  v = dppadd<0x124, 0xF>(v, v);  // row_ror:4
  v = dppadd<0x122, 0xF>(v, v);  // row_ror:2
  v = dppadd<0x121, 0xF>(v, v);  // row_ror:1
  return v;
}

// Full wave64 sum; lane 63 holds the total.
__device__ __forceinline__ float wave_sum63(float v) {
  v = row16_sum(v);
  v = dppadd<0x142, 0xA>(v, v);  // row_bcast:15 -> rows 1,3
  v = dppadd<0x143, 0xC>(v, v);  // row_bcast:31 -> rows 2,3
  return v;
}

__device__ __forceinline__ float blo(unsigned u) {
  return __uint_as_float(u << 16);
}
__device__ __forceinline__ float bhi(unsigned u) {
  return __uint_as_float(u & 0xFFFF0000u);
}
__device__ __forceinline__ f32x2 pkfma(f32x2 a, f32x2 b, f32x2 c) {
  return __builtin_elementwise_fma(a, b, c);
}

// dot of one bf16 weight row fragment (6 uint2) against h2
__device__ __forceinline__ float rowdot(const uint2* w, const f32x2 (&h2)[12]) {
  f32x2 a0 = {0.f, 0.f}, a1 = {0.f, 0.f};
#pragma unroll
  for (int c = 0; c < 6; ++c) {
    uint2 u = w[c];
    a0 = pkfma(f32x2{blo(u.x), bhi(u.x)}, h2[2 * c], a0);
    a1 = pkfma(f32x2{blo(u.y), bhi(u.y)}, h2[2 * c + 1], a1);
  }
  return row16_sum((a0.x + a1.x) + (a0.y + a1.y));
}

// FULL matvec: group g owns rows r = g + 32p, p=0..11.
// Rows p=0..5 (r<192) come from the LDS-staged bf16 Wh copy; rows p=6..11
// come from the PERSISTENT register slice wper (W_h is step-invariant --
// loaded once before the scan, never re-fetched). No VMEM in steady state.
__device__ __forceinline__ void matvec_full(
    const uint2* __restrict__ lwh, const uint2 (&wper)[36],
    const float* __restrict__ hs, const float* __restrict__ gzs,
    float* __restrict__ hbs, float& s1, float& s2,
    int g, int lane16, bool with_h)
{
  float rs[RPG];
  if (with_h) {
    f32x2 h2[12];
    const float4* h4 = (const float4*)hs;
#pragma unroll
    for (int c = 0; c < 6; ++c) {
      float4 hh = h4[lane16 + 16 * c];   // contiguous 16B/lane: conflict-free
      h2[2 * c]     = f32x2{hh.x, hh.y};
      h2[2 * c + 1] = f32x2{hh.z, hh.w};
    }
    // LDS rows p=0..5
#pragma unroll
    for (int p = 0; p < 6; ++p) {
      const int r = g + NG * p;
      f32x2 a0 = {0.f, 0.f}, a1 = {0.f, 0.f};
#pragma unroll
      for (int c = 0; c < 6; ++c) {
        uint2 u = lwh[r * LWSTR + lane16 + 16 * c];
        a0 = pkfma(f32x2{blo(u.x), bhi(u.x)}, h2[2 * c], a0);
        a1 = pkfma(f32x2{blo(u.y), bhi(u.y)}, h2[2 * c + 1], a1);
      }
      rs[p] = row16_sum((a0.x + a1.x) + (a0.y + a1.y));
    }
    // persistent register rows p=6..11
#pragma unroll
    for (int p = 0; p < 6; ++p)
      rs[6 + p] = rowdot(&wper[6 * p], h2);
  } else {
#pragma unroll
    for (int p = 0; p < RPG; ++p) rs[p] = 0.f;
  }
  if (lane16 == 0) {
#pragma unroll
    for (int p = 0; p < RPG; ++p) {
      const int r = g + NG * p;
      float vv = rs[p] + gzs[r];
      hbs[r] = vv;
      s1 += vv;
      s2 += vv * vv;
    }
  }
}

// Fallback matvec (no workspace): fp32 weights streamed, z from LDS.
__device__ __forceinline__ void matvec_ref(
    const float* __restrict__ Wh_f, const float* __restrict__ Wg_f,
    const float* __restrict__ hs, const float* __restrict__ zsh,
    const float (&bias)[RPG], float* __restrict__ hbs,
    float& s1, float& s2, int g, int lane16, bool with_h)
{
  f32x2 h2[12];
  if (with_h) {
    const float4* h4 = (const float4*)hs;
#pragma unroll
    for (int c = 0; c < 6; ++c) {
      float4 hh = h4[lane16 + 16 * c];
      h2[2 * c]     = f32x2{hh.x, hh.y};
      h2[2 * c + 1] = f32x2{hh.z, hh.w};
    }
  }
  float4 zz[3];
  const float4* z4 = (const float4*)zsh;
#pragma unroll
  for (int c = 0; c < 3; ++c) zz[c] = z4[lane16 + 16 * c];
#pragma unroll 2
  for (int p = 0; p < RPG; ++p) {
    const int r = g + NG * p;
    f32x2 a0 = {0.f, 0.f}, a1 = {0.f, 0.f};
    const float4* wg = (const float4*)Wg_f + (size_t)r * (DG / 4);
#pragma unroll
    for (int c = 0; c < 3; ++c) {
      float4 w = wg[lane16 + 16 * c];
      a0 = pkfma(f32x2{w.x, w.y}, f32x2{zz[c].x, zz[c].y}, a0);
      a1 = pkfma(f32x2{w.z, w.w}, f32x2{zz[c].z, zz[c].w}, a1);
    }
    if (with_h) {
      const float4* wh = (const float4*)Wh_f + (size_t)r * (DH / 4);
#pragma unroll
      for (int c = 0; c < 6; ++c) {
        float4 w = wh[lane16 + 16 * c];
        a0 = pkfma(f32x2{w.x, w.y}, h2[2 * c], a0);
        a1 = pkfma(f32x2{w.z, w.w}, h2[2 * c + 1], a1);
      }
    }
    float acc = row16_sum((a0.x + a1.x) + (a0.y + a1.y));
    if (lane16 == 0) {
      float vv = acc + bias[p];
      hbs[r] = vv;
      s1 += vv;
      s2 += vv * vv;
    }
  }
}

template <bool FULL>
__global__ __launch_bounds__(NT, 2) void fw_rnn_kernel(
    const float* __restrict__ z_seq,    // [T, B, DG]
    const float* __restrict__ Wh_f,     // [DH, DH] fp32
    const float* __restrict__ Wg_f,     // [DH, DG] fp32
    const ushort_t* __restrict__ Wh_b,  // bf16 copy (ws), FULL only
    const float* __restrict__ gz,       // [T, B, DH] Wg.z + b_h (fp32 Wg), FULL only
    const float* __restrict__ b_h,
    const float* __restrict__ ln_g,
    const float* __restrict__ ln_b,
    const float* __restrict__ alpha_fw,
    float* __restrict__ out)            // [B, DH]
{
  // 96 blocks on 256 CUs -> one block per CU: the full LDS pool is ours.
  __shared__ __align__(16) uint2 lwh[LWROWS * LWSTR];  // 149 KB staged Wh rows 0..191
  __shared__ __align__(16) float hs[DH];
  __shared__ __align__(16) float hbs[DH];
  __shared__ __align__(16) float gzs[DH];           // FULL: Wg.z+b_h for current t
  __shared__ __align__(16) float zsh[DG];           // !FULL only
  __shared__ float wlam[NSTEP];
  __shared__ __align__(16) float carr[48];          // carr[47] stays 0
  __shared__ __align__(16) float redA[NWAVE * 2];   // 16 floats
  __shared__ __align__(16) float redB[2][32];       // rows padded to 32

  const int tid    = threadIdx.x;
  const int b      = blockIdx.x;
  const int lane   = tid & 63, wv = tid >> 6;
  const int g      = tid >> 4, lane16 = tid & 15;
  const bool owner = (tid < DH);
  const bool zst   = (!FULL) && (tid >= DH) && (tid < DH + DG / 4);

  // persistent register slice of bf16 W_h: rows g+32p, p=6..11 (loaded ONCE)
  uint2 wper[36];
  if (FULL) {
    const uint2* wsrc = (const uint2*)Wh_b;
#pragma unroll
    for (int pp = 0; pp < 6; ++pp)
#pragma unroll
      for (int c = 0; c < 6; ++c)
        wper[pp * 6 + c] =
            wsrc[(size_t)(g + NG * (6 + pp)) * (DH / 4) + lane16 + 16 * c];
  }

  // stage Wh rows 0..191 into LDS (once)
  if (FULL) {
    const uint2* src = (const uint2*)Wh_b;
    for (int i = tid; i < LWROWS * 96; i += NT) {
      int row = i / 96, col = i - 96 * (i / 96);
      lwh[row * LWSTR + col] = src[(size_t)row * 96 + col];
    }
  }

  float bias[RPG];
#pragma unroll
  for (int p = 0; p < RPG; ++p) bias[p] = 0.f;
  if (!FULL && lane16 == 0) {
#pragma unroll
    for (int p = 0; p < RPG; ++p) bias[p] = b_h[g + NG * p];
  }
  float g_i = 0.f, be_i = 0.f;
  if (owner) { g_i = ln_g[tid]; be_i = ln_b[tid]; }

  const float af   = alpha_fw[0];
  const float kcur = (af >= 0.f) ? (1.f + log1pf(expf(af)))
                                 : (1.f / (1.f + log1pf(expf(-af))));
  const float invD = 1.0f / (float)DH;

  // Register-resident history column: hcol[tau] == h_committed[tau][tid] (owners).
  float hcol[48];
#pragma unroll
  for (int q = 0; q < 48; ++q) hcol[q] = 0.f;
  // phase-A register rows: group g serves tau=g (hregA) and tau=g+32 (hregB)
  float4 hregA[6], hregB[6];
#pragma unroll
  for (int c = 0; c < 6; ++c) {
    hregA[c] = float4{0.f, 0.f, 0.f, 0.f};
    hregB[c] = float4{0.f, 0.f, 0.f, 0.f};
  }

  // init: stage gzs for t=0 (FULL) / zsh (fallback); zero carr; pad redB
  if (FULL && tid < DH / 4)
    ((float4*)gzs)[tid] = ((const float4*)(gz + (size_t)b * DH))[tid];
  if (!FULL && tid < DG / 4)
    ((float4*)zsh)[tid] = ((const float4*)(z_seq + (size_t)b * DG))[tid];
  if (tid < 48) carr[tid] = 0.f;
  if (tid < 2) { redB[tid][30] = 0.f; redB[tid][31] = 0.f; }
  __syncthreads();

  float Shb = 0.f, Shb2 = 0.f;

  for (int t = 0; t < NSTEP; ++t) {
    // prefetch next step's gz into regs; written to gzs at commit
    float4 gzn = {0.f, 0.f, 0.f, 0.f};
    if (FULL && tid < DH / 4)
      gzn = ((const float4*)(gz + ((size_t)(t + 1) * BB + b) * DH))[tid];

    // ---------- base phase: h_base + fused LN stats ----------
    float s1 = 0.f, s2 = 0.f;
    if (FULL)
      matvec_full(lwh, wper, hs, gzs, hbs, s1, s2, g, lane16, t > 0);
    else
      matvec_ref(Wh_f, Wg_f, hs, zsh, bias, hbs, s1, s2, g, lane16, t > 0);

    // snapshot committed row(s) (hs == h_{t-1} until after barrier (a))
    if (t > 0) {
      if (g == t - 1) {
#pragma unroll
        for (int c = 0; c < 6; ++c) hregA[c] = ((const float4*)hs)[lane16 + 16 * c];
      }
      if (g + NG == t - 1) {
#pragma unroll
        for (int c = 0; c < 6; ++c) hregB[c] = ((const float4*)hs)[lane16 + 16 * c];
      }
    }
    {
      float v0 = wave_sum63(s1);
      float v1 = wave_sum63(s2);
      if (lane == 63) { redA[wv * 2] = v0; redA[wv * 2 + 1] = v1; }
    }
    __syncthreads();  // (a): hbs + redA visible

    float hb = 0.f, hsv = 0.f;
    if (owner) {
      float S1 = 0.f, S2 = 0.f;
      const float4* ra4 = (const float4*)redA;
#pragma unroll
      for (int q = 0; q < 4; ++q) {
        float4 ch = ra4[q];
        S1 += ch.x + ch.z;
        S2 += ch.y + ch.w;
      }
      Shb = S1; Shb2 = S2;
      hb = hbs[tid];
      float m   = S1 * invD;
      float var = S2 * invD - m * m;
      hsv = fmaxf((hb - m) * rsqrtf(var + 1e-5f) * g_i + be_i, 0.f);
      hs[tid] = hsv;
    }
    if (t == 0) {
      // A == 0: settling is identity. Commit, init wlam, stage next inputs.
      if (owner) hcol[0] = hsv;
      if (tid == 0) wlam[0] = 0.5f;
      if (FULL && tid < DH / 4) ((float4*)gzs)[tid] = gzn;
      if (zst)
        ((float4*)zsh)[tid - DH] =
            ((const float4*)(z_seq + ((size_t)1 * BB + b) * DG))[tid - DH];
      __syncthreads();  // (b)
      continue;
    }
    __syncthreads();  // (b): hs visible

    float4 znext;
    if (zst)
      znext = ((const float4*)(z_seq + ((size_t)(t + 1) * BB + b) * DG))[tid - DH];

    // ---------- settling iterations ----------
    for (int s = 0; s < SETI; ++s) {
      // phase A: carr[tau] = wlam_tau * (h_tau . h_s); group g serves tau=g, g+32
      if (g < t) {
        float4 ss[6];
        const float4* s4 = (const float4*)hs;
#pragma unroll
        for (int c = 0; c < 6; ++c) ss[c] = s4[lane16 + 16 * c];
        {
          f32x2 p0 = {0.f, 0.f}, p1 = {0.f, 0.f};
#pragma unroll
          for (int c = 0; c < 6; ++c) {
            p0 = pkfma(f32x2{hregA[c].x, hregA[c].y}, f32x2{ss[c].x, ss[c].y}, p0);
            p1 = pkfma(f32x2{hregA[c].z, hregA[c].w}, f32x2{ss[c].z, ss[c].w}, p1);
          }
          float p = row16_sum((p0.x + p1.x) + (p0.y + p1.y));
          if (lane16 == 0) carr[g] = p * wlam[g];
        }
        if (g + NG < t) {
          f32x2 p0 = {0.f, 0.f}, p1 = {0.f, 0.f};
#pragma unroll
          for (int c = 0; c < 6; ++c) {
            p0 = pkfma(f32x2{hregB[c].x, hregB[c].y}, f32x2{ss[c].x, ss[c].y}, p0);
            p1 = pkfma(f32x2{hregB[c].z, hregB[c].w}, f32x2{ss[c].z, ss[c].w}, p1);
          }
          float p = row16_sum((p0.x + p1.x) + (p0.y + p1.y));
          if (lane16 == 0) carr[g + NG] = p * wlam[g + NG];
        }
      }
      __syncthreads();  // (i): carr visible

      // phase B: owners compute Ah from registers + 5 partial sums via DPP
      float ah = 0.f;
      if (owner) {
        const float4* c4 = (const float4*)carr;
        float a0 = 0.f, a1 = 0.f, a2 = 0.f, a3 = 0.f;
#pragma unroll
        for (int q = 0; q < 12; ++q) {
          float4 cc = c4[q];
          a0 = fmaf(cc.x, hcol[4 * q + 0], a0);
          a1 = fmaf(cc.y, hcol[4 * q + 1], a1);
          a2 = fmaf(cc.z, hcol[4 * q + 2], a2);
          a3 = fmaf(cc.w, hcol[4 * q + 3], a3);
        }
        ah = (a0 + a2) + (a1 + a3);
        float v0 = wave_sum63(hsv * ah);
        float v1 = wave_sum63(hsv * hsv);
        float v2 = wave_sum63(ah * ah);
        float v3 = wave_sum63(hb * ah);
        float v4 = wave_sum63(ah);
        if (lane == 63) {
          float* rb = redB[s & 1];
          rb[wv * 5 + 0] = v0; rb[wv * 5 + 1] = v1; rb[wv * 5 + 2] = v2;
          rb[wv * 5 + 3] = v3; rb[wv * 5 + 4] = v4;
        }
      }
      __syncthreads();  // (ii): redB visible

      // phase C: gate + analytic LN + commit
      if (owner) {
        const float4* rb4 = (const float4*)redB[s & 1];
        float S[5] = {0.f, 0.f, 0.f, 0.f, 0.f};
#pragma unroll
        for (int q = 0; q < 8; ++q) {
          float4 ch = rb4[q];
          S[(4 * q + 0) % 5] += ch.x;
          S[(4 * q + 1) % 5] += ch.y;
          S[(4 * q + 2) % 5] += ch.z;
          S[(4 * q + 3) % 5] += ch.w;
        }
        float n1 = fmaxf(sqrtf(S[1]), 1e-6f);
        float n2 = fmaxf(sqrtf(S[2]), 1e-6f);
        float R  = fminf(fmaxf(__fdividef(S[0], n1 * n2), 0.f), 1.f);
        float a  = 1.f - __expf(kcur * __logf(1.f - R));
        float beta = 1.f - a * a;
        float mu  = (beta * Shb + a * S[4]) * invD;
        float Exx = (beta * beta * Shb2 + 2.f * beta * a * S[3] + a * a * S[2]) * invD;
        float var = Exx - mu * mu;
        float xv  = beta * hb + a * ah;
        hsv = fmaxf((xv - mu) * rsqrtf(var + 1e-5f) * g_i + be_i, 0.f);
        hs[tid] = hsv;
        if (s == SETI - 1) {
#pragma unroll
          for (int q = 0; q < 48; ++q)
            if (q == t) hcol[q] = hsv;
        }
      }
      if (s == SETI - 1) {
        if (tid < t) wlam[tid] *= 0.9f;
        else if (tid == t) wlam[tid] = 0.5f;
        if (FULL && tid < DH / 4) ((float4*)gzs)[tid] = gzn;
        if (zst) ((float4*)zsh)[tid - DH] = znext;
      }
      __syncthreads();  // (iii)
    }
  }

  // ================= final (query) step (gzs holds gz[NSTEP]) =================
  {
    float s1 = 0.f, s2 = 0.f;
    if (FULL)
      matvec_full(lwh, wper, hs, gzs, hbs, s1, s2, g, lane16, true);
    else
      matvec_ref(Wh_f, Wg_f, hs, zsh, bias, hbs, s1, s2, g, lane16, true);
    if (g + NG == NSTEP - 1) {  // last committed row -> hregB (g = 14)
#pragma unroll
      for (int c = 0; c < 6; ++c) hregB[c] = ((const float4*)hs)[lane16 + 16 * c];
    }
    {
      float v0 = wave_sum63(s1);
      float v1 = wave_sum63(s2);
      if (lane == 63) { redA[wv * 2] = v0; redA[wv * 2 + 1] = v1; }
    }
    __syncthreads();

    float hb = 0.f, hv = 0.f;
    if (owner) {
      float S1 = 0.f, S2 = 0.f;
      const float4* ra4 = (const float4*)redA;
#pragma unroll
      for (int q = 0; q < 4; ++q) {
        float4 ch = ra4[q];
        S1 += ch.x + ch.z;
        S2 += ch.y + ch.w;
      }
      Shb = S1; Shb2 = S2;
      hb = hbs[tid];
      float m   = S1 * invD;
      float var = S2 * invD - m * m;
      hv = fmaxf((hb - m) * rsqrtf(var + 1e-5f) * g_i + be_i, 0.f);
      hs[tid] = hv;
    }
    __syncthreads();

    for (int s = 0; s < SETI; ++s) {
      // phase A: all 48 taus (g always < NSTEP; g+32 < NSTEP for g < 15)
      {
        float4 ss[6];
        const float4* s4 = (const float4*)hs;
#pragma unroll
        for (int c = 0; c < 6; ++c) ss[c] = s4[lane16 + 16 * c];
        {
          f32x2 p0 = {0.f, 0.f}, p1 = {0.f, 0.f};
#pragma unroll
          for (int c = 0; c < 6; ++c) {
            p0 = pkfma(f32x2{hregA[c].x, hregA[c].y}, f32x2{ss[c].x, ss[c].y}, p0);
            p1 = pkfma(f32x2{hregA[c].z, hregA[c].w}, f32x2{ss[c].z, ss[c].w}, p1);
          }
          float p = row16_sum((p0.x + p1.x) + (p0.y + p1.y));
          if (lane16 == 0) carr[g] = p * wlam[g];
        }
        if (g + NG < NSTEP) {
          f32x2 p0 = {0.f, 0.f}, p1 = {0.f, 0.f};
#pragma unroll
          for (int c = 0; c < 6; ++c) {
            p0 = pkfma(f32x2{hregB[c].x, hregB[c].y}, f32x2{ss[c].x, ss[c].y}, p0);
            p1 = pkfma(f32x2{hregB[c].z, hregB[c].w}, f32x2{ss[c].z, ss[c].w}, p1);
          }
          float p = row16_sum((p0.x + p1.x) + (p0.y + p1.y));
          if (lane16 == 0) carr[g + NG] = p * wlam[g + NG];
        }
      }
      __syncthreads();

      float ah = 0.f;
      if (owner) {
        const float4* c4 = (const float4*)carr;
        float a0 = 0.f, a1 = 0.f, a2 = 0.f, a3 = 0.f;
#pragma unroll
        for (int q = 0; q < 12; ++q) {
          float4 cc = c4[q];
          a0 = fmaf(cc.x, hcol[4 * q + 0], a0);
          a1 = fmaf(cc.y, hcol[4 * q + 1], a1);
          a2 = fmaf(cc.z, hcol[4 * q + 2], a2);
          a3 = fmaf(cc.w, hcol[4 * q + 3], a3);
        }
        ah = (a0 + a2) + (a1 + a3);
        float v0 = wave_sum63(ah);
        float v1 = wave_sum63(ah * ah);
        float v2 = wave_sum63(hb * ah);
        if (lane == 63) {
          float* rb = redB[s & 1];
          rb[wv * 5 + 0] = v0; rb[wv * 5 + 1] = v1; rb[wv * 5 + 2] = v2;
        }
      }
      __syncthreads();

      if (owner) {
        const float4* rb4 = (const float4*)redB[s & 1];
        float S[5] = {0.f, 0.f, 0.f, 0.f, 0.f};
#pragma unroll
        for (int q = 0; q < 8; ++q) {
          float4 ch = rb4[q];
          S[(4 * q + 0) % 5] += ch.x;
          S[(4 * q + 1) % 5] += ch.y;
          S[(4 * q + 2) % 5] += ch.z;
          S[(4 * q + 3) % 5] += ch.w;
        }
        // xv = hb + ah : analytic stats (S[0]=sum ah, S[1]=sum ah^2, S[2]=sum hb*ah)
        float Sx  = Shb + S[0];
        float Sxx = Shb2 + 2.f * S[2] + S[1];
        float mu  = Sx * invD;
        float var = Sxx * invD - mu * mu;
        float xv  = hb + ah;
        hv = fmaxf((xv - mu) * rsqrtf(var + 1e-5f) * g_i + be_i, 0.f);
        if (s < SETI - 1) hs[tid] = hv;
      }
      if (s < SETI - 1) __syncthreads();
    }

    if (owner) out[(size_t)b * DH + tid] = hv;
  }
}

// Prologue (one launch): bf16-convert W_h AND compute
// gz[t][b][r] = fp32 W_g[r,:] . z[t][b] + b_h[r].
// grid (BB, 8): block (b, y) handles t = 6y..6y+5, Wg slice held in registers.
__global__ __launch_bounds__(PREPNT) void prep_kernel(
    const float* __restrict__ z_seq, const float* __restrict__ Wg,
    const float* __restrict__ W_h, const float* __restrict__ b_h,
    ushort_t* __restrict__ Whb, float* __restrict__ gz)
{
  __shared__ __align__(16) float zsh[DG];
  const int tid = threadIdx.x, b = blockIdx.x;
  const int g = tid >> 4, lane16 = tid & 15;

  // fold-in: fp32 -> bf16 (RTN-even) for W_h
  {
    int lid = (blockIdx.y * BB + blockIdx.x) * PREPNT + tid;
    if (lid < DH * DH) {
      unsigned u = __float_as_uint(W_h[lid]);
      unsigned r = (u + 0x7FFFu + ((u >> 16) & 1u)) >> 16;
      Whb[lid] = (ushort_t)r;
    }
  }

  float4 w[24];
#pragma unroll
  for (int p = 0; p < 8; ++p)
#pragma unroll
    for (int c = 0; c < 3; ++c)
      w[p * 3 + c] = ((const float4*)Wg)[(size_t)(8 * g + p) * (DG / 4) + lane16 + 16 * c];
  float4 bs0 = {0.f, 0.f, 0.f, 0.f}, bs1 = {0.f, 0.f, 0.f, 0.f};
  if (lane16 == 0) {
    bs0 = ((const float4*)b_h)[2 * g];
    bs1 = ((const float4*)b_h)[2 * g + 1];
  }
  for (int tt = 0; tt < 6; ++tt) {
    const int t = blockIdx.y * 6 + tt;
    __syncthreads();
    if (tid < DG / 4)
      ((float4*)zsh)[tid] = ((const float4*)(z_seq + ((size_t)t * BB + b) * DG))[tid];
    __syncthreads();
    float4 zz[3];
#pragma unroll
    for (int c = 0; c < 3; ++c) zz[c] = ((const float4*)zsh)[lane16 + 16 * c];
    float rs[8];
#pragma unroll
    for (int p = 0; p < 8; ++p) {
      f32x2 a0 = {0.f, 0.f}, a1 = {0.f, 0.f};
#pragma unroll
      for (int c = 0; c < 3; ++c) {
        a0 = pkfma(f32x2{w[p * 3 + c].x, w[p * 3 + c].y}, f32x2{zz[c].x, zz[c].y}, a0);
        a1 = pkfma(f32x2{w[p * 3 + c].z, w[p * 3 + c].w}, f32x2{zz[c].z, zz[c].w}, a1);
      }
      rs[p] = row16_sum((a0.x + a1.x) + (a0.y + a1.y));
    }
    if (lane16 == 0) {
      float* grow = gz + ((size_t)t * BB + b) * DH + 8 * g;
      ((float4*)grow)[0] = float4{rs[0] + bs0.x, rs[1] + bs0.y, rs[2] + bs0.z, rs[3] + bs0.w};
      ((float4*)grow)[1] = float4{rs[4] + bs1.x, rs[5] + bs1.y, rs[6] + bs1.z, rs[7] + bs1.w};
    }
  }
}

extern "C" void kernel_launch(void* const* d_in, const int* in_sizes, int n_in,
                              void* d_out, int out_size, void* d_ws, size_t ws_size,
                              hipStream_t stream) {
  const float* z_seq    = (const float*)d_in[0];
  const float* W_h      = (const float*)d_in[1];
  const float* W_g      = (const float*)d_in[2];
  const float* b_h      = (const float*)d_in[3];
  const float* ln_g     = (const float*)d_in[4];
  const float* ln_b     = (const float*)d_in[5];
  const float* alpha_fw = (const float*)d_in[6];
  float* out = (float*)d_out;

  const size_t nWh = (size_t)DH * DH;                              // 147456
  const size_t bf16Bytes = nWh * sizeof(ushort_t);                 // 294912
  const size_t gzBytes   = (size_t)TT * BB * DH * sizeof(float);   // 7077888

  if (ws_size >= bf16Bytes + gzBytes) {
    ushort_t* Whb = (ushort_t*)d_ws;
    float* gz = (float*)((char*)d_ws + bf16Bytes);
    prep_kernel<<<dim3(BB, 8), dim3(PREPNT), 0, stream>>>(
        z_seq, W_g, W_h, b_h, Whb, gz);
    fw_rnn_kernel<true><<<dim3(BB), dim3(NT), 0, stream>>>(
        z_seq, W_h, W_g, Whb, gz, b_h, ln_g, ln_b, alpha_fw, out);
  } else {
    fw_rnn_kernel<false><<<dim3(BB), dim3(NT), 0, stream>>>(
        z_seq, W_h, W_g, nullptr, nullptr, b_h, ln_g, ln_b, alpha_fw, out);
  }
}

// Round 10
// 524.864 us; speedup vs baseline: 1.3877x; 1.3877x over previous
//
#include <hip/hip_runtime.h>
#include <math.h>

// Problem constants
#define TT    48
#define BB    96
#define DG    192
#define DH    384
#define NSTEP 47     // T-1 scan steps
#define SETI  3      // inner settling iterations
#define NT    512    // threads per block (8 waves = 2/SIMD -> 256-reg budget)
#define NWAVE 8      // 512/64
#define NOW   6      // owner waves (tid < DH)
#define NG    32     // 16-lane groups per block
#define RPG   12     // rows per group (384/32)
#define LWROWS 192   // Wh rows staged in LDS (rows 0..191)
#define LWSTR  97    // uint2 stride per staged row (96 + 1 pad)
#define PREPNT 768   // prep kernel block size

typedef unsigned short ushort_t;
typedef float f32x2 __attribute__((ext_vector_type(2)));

// ---------- DPP-based reductions (VALU latency, not LDS latency) ----------
template <int CTRL, int RM>
__device__ __forceinline__ float dppadd(float acc, float x) {
  int t = __builtin_amdgcn_update_dpp(0, __float_as_int(x), CTRL, RM, 0xF, false);
  return acc + __int_as_float(t);
}

// Sum of 16 lanes within each row; every lane of the row gets the total.
__device__ __forceinline__ float row16_sum(float v) {
  v = dppadd<0x128, 0xF>(v, v);  // row_ror:8
  v = dppadd<0x124, 0xF>(v, v);  // row_ror:4
  v = dppadd<0x122, 0xF>(v, v);  // row_ror:2
  v = dppadd<0x121, 0xF>(v, v);  // row_ror:1
  return v;
}

// Full wave64 sum; lane 63 holds the total.
__device__ __forceinline__ float wave_sum63(float v) {
  v = row16_sum(v);
  v = dppadd<0x142, 0xA>(v, v);  // row_bcast:15 -> rows 1,3
  v = dppadd<0x143, 0xC>(v, v);  // row_bcast:31 -> rows 2,3
  return v;
}

__device__ __forceinline__ float blo(unsigned u) {
  return __uint_as_float(u << 16);
}
__device__ __forceinline__ float bhi(unsigned u) {
  return __uint_as_float(u & 0xFFFF0000u);
}
__device__ __forceinline__ f32x2 pkfma(f32x2 a, f32x2 b, f32x2 c) {
  return __builtin_elementwise_fma(a, b, c);
}

// dot of one bf16 weight row fragment (6 uint2) against h2
__device__ __forceinline__ float rowdot(const uint2* w, const f32x2 (&h2)[12]) {
  f32x2 a0 = {0.f, 0.f}, a1 = {0.f, 0.f};
#pragma unroll
  for (int c = 0; c < 6; ++c) {
    uint2 u = w[c];
    a0 = pkfma(f32x2{blo(u.x), bhi(u.x)}, h2[2 * c], a0);
    a1 = pkfma(f32x2{blo(u.y), bhi(u.y)}, h2[2 * c + 1], a1);
  }
  return row16_sum((a0.x + a1.x) + (a0.y + a1.y));
}

// FULL matvec: group g owns rows r = g + 32p, p=0..11.
// Rows p=0..5 (r<192) come from the LDS-staged bf16 Wh copy; rows p=6..11
// stream from L2 as a 3-deep pipeline of 2-row batches (12 uint2 = 24 regs
// each, max 2 batches + h2 = 72 transient regs -> no scratch spill, unlike
// R8's 2x18 batches at 96 peak). b0/b1 latency hides under the 6 LDS rows;
// b2 hides under b0/b1 consumption. gzs has Wg.z + b_h.
__device__ __forceinline__ void matvec_full(
    const uint2* __restrict__ lwh, const ushort_t* __restrict__ Wh_b,
    const float* __restrict__ hs, const float* __restrict__ gzs,
    float* __restrict__ hbs, float& s1, float& s2,
    int g, int lane16, bool with_h)
{
  float rs[RPG];
  if (with_h) {
    const uint2* wsrc = (const uint2*)Wh_b;
    // issue batch 0 (rows p=6,7)
    uint2 uw0[12];
#pragma unroll
    for (int pp = 0; pp < 2; ++pp)
#pragma unroll
      for (int c = 0; c < 6; ++c)
        uw0[pp * 6 + c] =
            wsrc[(size_t)(g + NG * (6 + pp)) * (DH / 4) + lane16 + 16 * c];
    f32x2 h2[12];
    const float4* h4 = (const float4*)hs;
#pragma unroll
    for (int c = 0; c < 6; ++c) {
      float4 hh = h4[lane16 + 16 * c];   // contiguous 16B/lane: conflict-free
      h2[2 * c]     = f32x2{hh.x, hh.y};
      h2[2 * c + 1] = f32x2{hh.z, hh.w};
    }
    // issue batch 1 (rows p=8,9)
    uint2 uw1[12];
#pragma unroll
    for (int pp = 0; pp < 2; ++pp)
#pragma unroll
      for (int c = 0; c < 6; ++c)
        uw1[pp * 6 + c] =
            wsrc[(size_t)(g + NG * (8 + pp)) * (DH / 4) + lane16 + 16 * c];
    // LDS rows p=0..5 (~600 cy of ds_read+FMA covers b0/b1 L2 latency)
#pragma unroll
    for (int p = 0; p < 6; ++p) {
      const int r = g + NG * p;
      f32x2 a0 = {0.f, 0.f}, a1 = {0.f, 0.f};
#pragma unroll
      for (int c = 0; c < 6; ++c) {
        uint2 u = lwh[r * LWSTR + lane16 + 16 * c];
        a0 = pkfma(f32x2{blo(u.x), bhi(u.x)}, h2[2 * c], a0);
        a1 = pkfma(f32x2{blo(u.y), bhi(u.y)}, h2[2 * c + 1], a1);
      }
      rs[p] = row16_sum((a0.x + a1.x) + (a0.y + a1.y));
    }
    // consume b0; issue b2 (rows p=10,11); consume b1; consume b2
    rs[6] = rowdot(uw0, h2);
    rs[7] = rowdot(uw0 + 6, h2);
    uint2 uw2[12];
#pragma unroll
    for (int pp = 0; pp < 2; ++pp)
#pragma unroll
      for (int c = 0; c < 6; ++c)
        uw2[pp * 6 + c] =
            wsrc[(size_t)(g + NG * (10 + pp)) * (DH / 4) + lane16 + 16 * c];
    rs[8] = rowdot(uw1, h2);
    rs[9] = rowdot(uw1 + 6, h2);
    rs[10] = rowdot(uw2, h2);
    rs[11] = rowdot(uw2 + 6, h2);
  } else {
#pragma unroll
    for (int p = 0; p < RPG; ++p) rs[p] = 0.f;
  }
  if (lane16 == 0) {
#pragma unroll
    for (int p = 0; p < RPG; ++p) {
      const int r = g + NG * p;
      float vv = rs[p] + gzs[r];
      hbs[r] = vv;
      s1 += vv;
      s2 += vv * vv;
    }
  }
}

// Fallback matvec (no workspace): fp32 weights streamed, z from LDS.
__device__ __forceinline__ void matvec_ref(
    const float* __restrict__ Wh_f, const float* __restrict__ Wg_f,
    const float* __restrict__ hs, const float* __restrict__ zsh,
    const float (&bias)[RPG], float* __restrict__ hbs,
    float& s1, float& s2, int g, int lane16, bool with_h)
{
  f32x2 h2[12];
  if (with_h) {
    const float4* h4 = (const float4*)hs;
#pragma unroll
    for (int c = 0; c < 6; ++c) {
      float4 hh = h4[lane16 + 16 * c];
      h2[2 * c]     = f32x2{hh.x, hh.y};
      h2[2 * c + 1] = f32x2{hh.z, hh.w};
    }
  }
  float4 zz[3];
  const float4* z4 = (const float4*)zsh;
#pragma unroll
  for (int c = 0; c < 3; ++c) zz[c] = z4[lane16 + 16 * c];
#pragma unroll 2
  for (int p = 0; p < RPG; ++p) {
    const int r = g + NG * p;
    f32x2 a0 = {0.f, 0.f}, a1 = {0.f, 0.f};
    const float4* wg = (const float4*)Wg_f + (size_t)r * (DG / 4);
#pragma unroll
    for (int c = 0; c < 3; ++c) {
      float4 w = wg[lane16 + 16 * c];
      a0 = pkfma(f32x2{w.x, w.y}, f32x2{zz[c].x, zz[c].y}, a0);
      a1 = pkfma(f32x2{w.z, w.w}, f32x2{zz[c].z, zz[c].w}, a1);
    }
    if (with_h) {
      const float4* wh = (const float4*)Wh_f + (size_t)r * (DH / 4);
#pragma unroll
      for (int c = 0; c < 6; ++c) {
        float4 w = wh[lane16 + 16 * c];
        a0 = pkfma(f32x2{w.x, w.y}, h2[2 * c], a0);
        a1 = pkfma(f32x2{w.z, w.w}, h2[2 * c + 1], a1);
      }
    }
    float acc = row16_sum((a0.x + a1.x) + (a0.y + a1.y));
    if (lane16 == 0) {
      float vv = acc + bias[p];
      hbs[r] = vv;
      s1 += vv;
      s2 += vv * vv;
    }
  }
}

template <bool FULL>
__global__ __launch_bounds__(NT, 2) void fw_rnn_kernel(
    const float* __restrict__ z_seq,    // [T, B, DG]
    const float* __restrict__ Wh_f,     // [DH, DH] fp32
    const float* __restrict__ Wg_f,     // [DH, DG] fp32
    const ushort_t* __restrict__ Wh_b,  // bf16 copy (ws), FULL only
    const float* __restrict__ gz,       // [T, B, DH] Wg.z + b_h (fp32 Wg), FULL only
    const float* __restrict__ b_h,
    const float* __restrict__ ln_g,
    const float* __restrict__ ln_b,
    const float* __restrict__ alpha_fw,
    float* __restrict__ out)            // [B, DH]
{
  // 96 blocks on 256 CUs -> one block per CU: the full LDS pool is ours.
  __shared__ __align__(16) uint2 lwh[LWROWS * LWSTR];  // 149 KB staged Wh rows 0..191
  __shared__ __align__(16) float hs[DH];
  __shared__ __align__(16) float hbs[DH];
  __shared__ __align__(16) float gzs[DH];           // FULL: Wg.z+b_h for current t
  __shared__ __align__(16) float zsh[DG];           // !FULL only
  __shared__ float wlam[NSTEP];
  __shared__ __align__(16) float carr[48];          // carr[47] stays 0
  __shared__ __align__(16) float redA[NWAVE * 2];   // 16 floats
  __shared__ __align__(16) float redB[2][32];       // rows padded to 32

  const int tid    = threadIdx.x;
  const int b      = blockIdx.x;
  const int lane   = tid & 63, wv = tid >> 6;
  const int g      = tid >> 4, lane16 = tid & 15;
  const bool owner = (tid < DH);
  const bool zst   = (!FULL) && (tid >= DH) && (tid < DH + DG / 4);

  // stage Wh rows 0..191 into LDS (once)
  if (FULL) {
    const uint2* src = (const uint2*)Wh_b;
    for (int i = tid; i < LWROWS * 96; i += NT) {
      int row = i / 96, col = i - 96 * (i / 96);
      lwh[row * LWSTR + col] = src[(size_t)row * 96 + col];
    }
  }

  float bias[RPG];
#pragma unroll
  for (int p = 0; p < RPG; ++p) bias[p] = 0.f;
  if (!FULL && lane16 == 0) {
#pragma unroll
    for (int p = 0; p < RPG; ++p) bias[p] = b_h[g + NG * p];
  }
  float g_i = 0.f, be_i = 0.f;
  if (owner) { g_i = ln_g[tid]; be_i = ln_b[tid]; }

  const float af   = alpha_fw[0];
  const float kcur = (af >= 0.f) ? (1.f + log1pf(expf(af)))
                                 : (1.f / (1.f + log1pf(expf(-af))));
  const float invD = 1.0f / (float)DH;

  // Register-resident history column: hcol[tau] == h_committed[tau][tid] (owners).
  float hcol[48];
#pragma unroll
  for (int q = 0; q < 48; ++q) hcol[q] = 0.f;
  // phase-A register rows: group g serves tau=g (hregA) and tau=g+32 (hregB)
  float4 hregA[6], hregB[6];
#pragma unroll
  for (int c = 0; c < 6; ++c) {
    hregA[c] = float4{0.f, 0.f, 0.f, 0.f};
    hregB[c] = float4{0.f, 0.f, 0.f, 0.f};
  }

  // init: stage gzs for t=0 (FULL) / zsh (fallback); zero carr; pad redB
  if (FULL && tid < DH / 4)
    ((float4*)gzs)[tid] = ((const float4*)(gz + (size_t)b * DH))[tid];
  if (!FULL && tid < DG / 4)
    ((float4*)zsh)[tid] = ((const float4*)(z_seq + (size_t)b * DG))[tid];
  if (tid < 48) carr[tid] = 0.f;
  if (tid < 2) { redB[tid][30] = 0.f; redB[tid][31] = 0.f; }
  __syncthreads();

  float Shb = 0.f, Shb2 = 0.f;

  for (int t = 0; t < NSTEP; ++t) {
    // prefetch next step's gz into regs; written to gzs at commit
    float4 gzn = {0.f, 0.f, 0.f, 0.f};
    if (FULL && tid < DH / 4)
      gzn = ((const float4*)(gz + ((size_t)(t + 1) * BB + b) * DH))[tid];

    // ---------- base phase: h_base + fused LN stats ----------
    float s1 = 0.f, s2 = 0.f;
    if (FULL)
      matvec_full(lwh, Wh_b, hs, gzs, hbs, s1, s2, g, lane16, t > 0);
    else
      matvec_ref(Wh_f, Wg_f, hs, zsh, bias, hbs, s1, s2, g, lane16, t > 0);

    // snapshot committed row(s) (hs == h_{t-1} until after barrier (a))
    if (t > 0) {
      if (g == t - 1) {
#pragma unroll
        for (int c = 0; c < 6; ++c) hregA[c] = ((const float4*)hs)[lane16 + 16 * c];
      }
      if (g + NG == t - 1) {
#pragma unroll
        for (int c = 0; c < 6; ++c) hregB[c] = ((const float4*)hs)[lane16 + 16 * c];
      }
    }
    {
      float v0 = wave_sum63(s1);
      float v1 = wave_sum63(s2);
      if (lane == 63) { redA[wv * 2] = v0; redA[wv * 2 + 1] = v1; }
    }
    __syncthreads();  // (a): hbs + redA visible

    float hb = 0.f, hsv = 0.f;
    if (owner) {
      float S1 = 0.f, S2 = 0.f;
      const float4* ra4 = (const float4*)redA;
#pragma unroll
      for (int q = 0; q < 4; ++q) {
        float4 ch = ra4[q];
        S1 += ch.x + ch.z;
        S2 += ch.y + ch.w;
      }
      Shb = S1; Shb2 = S2;
      hb = hbs[tid];
      float m   = S1 * invD;
      float var = S2 * invD - m * m;
      hsv = fmaxf((hb - m) * rsqrtf(var + 1e-5f) * g_i + be_i, 0.f);
      hs[tid] = hsv;
    }
    if (t == 0) {
      // A == 0: settling is identity. Commit, init wlam, stage next inputs.
      if (owner) hcol[0] = hsv;
      if (tid == 0) wlam[0] = 0.5f;
      if (FULL && tid < DH / 4) ((float4*)gzs)[tid] = gzn;
      if (zst)
        ((float4*)zsh)[tid - DH] =
            ((const float4*)(z_seq + ((size_t)1 * BB + b) * DG))[tid - DH];
      __syncthreads();  // (b)
      continue;
    }
    __syncthreads();  // (b): hs visible

    float4 znext;
    if (zst)
      znext = ((const float4*)(z_seq + ((size_t)(t + 1) * BB + b) * DG))[tid - DH];

    // ---------- settling iterations ----------
    for (int s = 0; s < SETI; ++s) {
      // phase A: carr[tau] = wlam_tau * (h_tau . h_s); group g serves tau=g, g+32
      if (g < t) {
        float4 ss[6];
        const float4* s4 = (const float4*)hs;
#pragma unroll
        for (int c = 0; c < 6; ++c) ss[c] = s4[lane16 + 16 * c];
        {
          f32x2 p0 = {0.f, 0.f}, p1 = {0.f, 0.f};
#pragma unroll
          for (int c = 0; c < 6; ++c) {
            p0 = pkfma(f32x2{hregA[c].x, hregA[c].y}, f32x2{ss[c].x, ss[c].y}, p0);
            p1 = pkfma(f32x2{hregA[c].z, hregA[c].w}, f32x2{ss[c].z, ss[c].w}, p1);
          }
          float p = row16_sum((p0.x + p1.x) + (p0.y + p1.y));
          if (lane16 == 0) carr[g] = p * wlam[g];
        }
        if (g + NG < t) {
          f32x2 p0 = {0.f, 0.f}, p1 = {0.f, 0.f};
#pragma unroll
          for (int c = 0; c < 6; ++c) {
            p0 = pkfma(f32x2{hregB[c].x, hregB[c].y}, f32x2{ss[c].x, ss[c].y}, p0);
            p1 = pkfma(f32x2{hregB[c].z, hregB[c].w}, f32x2{ss[c].z, ss[c].w}, p1);
          }
          float p = row16_sum((p0.x + p1.x) + (p0.y + p1.y));
          if (lane16 == 0) carr[g + NG] = p * wlam[g + NG];
        }
      }
      __syncthreads();  // (i): carr visible

      // phase B: owners compute Ah from registers + 5 partial sums via DPP
      float ah = 0.f;
      if (owner) {
        const float4* c4 = (const float4*)carr;
        float a0 = 0.f, a1 = 0.f, a2 = 0.f, a3 = 0.f;
#pragma unroll
        for (int q = 0; q < 12; ++q) {
          float4 cc = c4[q];
          a0 = fmaf(cc.x, hcol[4 * q + 0], a0);
          a1 = fmaf(cc.y, hcol[4 * q + 1], a1);
          a2 = fmaf(cc.z, hcol[4 * q + 2], a2);
          a3 = fmaf(cc.w, hcol[4 * q + 3], a3);
        }
        ah = (a0 + a2) + (a1 + a3);
        float v0 = wave_sum63(hsv * ah);
        float v1 = wave_sum63(hsv * hsv);
        float v2 = wave_sum63(ah * ah);
        float v3 = wave_sum63(hb * ah);
        float v4 = wave_sum63(ah);
        if (lane == 63) {
          float* rb = redB[s & 1];
          rb[wv * 5 + 0] = v0; rb[wv * 5 + 1] = v1; rb[wv * 5 + 2] = v2;
          rb[wv * 5 + 3] = v3; rb[wv * 5 + 4] = v4;
        }
      }
      __syncthreads();  // (ii): redB visible

      // phase C: gate + analytic LN + commit
      if (owner) {
        const float4* rb4 = (const float4*)redB[s & 1];
        float S[5] = {0.f, 0.f, 0.f, 0.f, 0.f};
#pragma unroll
        for (int q = 0; q < 8; ++q) {
          float4 ch = rb4[q];
          S[(4 * q + 0) % 5] += ch.x;
          S[(4 * q + 1) % 5] += ch.y;
          S[(4 * q + 2) % 5] += ch.z;
          S[(4 * q + 3) % 5] += ch.w;
        }
        float n1 = fmaxf(sqrtf(S[1]), 1e-6f);
        float n2 = fmaxf(sqrtf(S[2]), 1e-6f);
        float R  = fminf(fmaxf(__fdividef(S[0], n1 * n2), 0.f), 1.f);
        float a  = 1.f - __expf(kcur * __logf(1.f - R));
        float beta = 1.f - a * a;
        float mu  = (beta * Shb + a * S[4]) * invD;
        float Exx = (beta * beta * Shb2 + 2.f * beta * a * S[3] + a * a * S[2]) * invD;
        float var = Exx - mu * mu;
        float xv  = beta * hb + a * ah;
        hsv = fmaxf((xv - mu) * rsqrtf(var + 1e-5f) * g_i + be_i, 0.f);
        hs[tid] = hsv;
        if (s == SETI - 1) {
#pragma unroll
          for (int q = 0; q < 48; ++q)
            if (q == t) hcol[q] = hsv;
        }
      }
      if (s == SETI - 1) {
        if (tid < t) wlam[tid] *= 0.9f;
        else if (tid == t) wlam[tid] = 0.5f;
        if (FULL && tid < DH / 4) ((float4*)gzs)[tid] = gzn;
        if (zst) ((float4*)zsh)[tid - DH] = znext;
      }
      __syncthreads();  // (iii)
    }
  }

  // ================= final (query) step (gzs holds gz[NSTEP]) =================
  {
    float s1 = 0.f, s2 = 0.f;
    if (FULL)
      matvec_full(lwh, Wh_b, hs, gzs, hbs, s1, s2, g, lane16, true);
    else
      matvec_ref(Wh_f, Wg_f, hs, zsh, bias, hbs, s1, s2, g, lane16, true);
    if (g + NG == NSTEP - 1) {  // last committed row -> hregB (g = 14)
#pragma unroll
      for (int c = 0; c < 6; ++c) hregB[c] = ((const float4*)hs)[lane16 + 16 * c];
    }
    {
      float v0 = wave_sum63(s1);
      float v1 = wave_sum63(s2);
      if (lane == 63) { redA[wv * 2] = v0; redA[wv * 2 + 1] = v1; }
    }
    __syncthreads();

    float hb = 0.f, hv = 0.f;
    if (owner) {
      float S1 = 0.f, S2 = 0.f;
      const float4* ra4 = (const float4*)redA;
#pragma unroll
      for (int q = 0; q < 4; ++q) {
        float4 ch = ra4[q];
        S1 += ch.x + ch.z;
        S2 += ch.y + ch.w;
      }
      Shb = S1; Shb2 = S2;
      hb = hbs[tid];
      float m   = S1 * invD;
      float var = S2 * invD - m * m;
      hv = fmaxf((hb - m) * rsqrtf(var + 1e-5f) * g_i + be_i, 0.f);
      hs[tid] = hv;
    }
    __syncthreads();

    for (int s = 0; s < SETI; ++s) {
      // phase A: all 48 taus (g always < NSTEP; g+32 < NSTEP for g < 15)
      {
        float4 ss[6];
        const float4* s4 = (const float4*)hs;
#pragma unroll
        for (int c = 0; c < 6; ++c) ss[c] = s4[lane16 + 16 * c];
        {
          f32x2 p0 = {0.f, 0.f}, p1 = {0.f, 0.f};
#pragma unroll
          for (int c = 0; c < 6; ++c) {
            p0 = pkfma(f32x2{hregA[c].x, hregA[c].y}, f32x2{ss[c].x, ss[c].y}, p0);
            p1 = pkfma(f32x2{hregA[c].z, hregA[c].w}, f32x2{ss[c].z, ss[c].w}, p1);
          }
          float p = row16_sum((p0.x + p1.x) + (p0.y + p1.y));
          if (lane16 == 0) carr[g] = p * wlam[g];
        }
        if (g + NG < NSTEP) {
          f32x2 p0 = {0.f, 0.f}, p1 = {0.f, 0.f};
#pragma unroll
          for (int c = 0; c < 6; ++c) {
            p0 = pkfma(f32x2{hregB[c].x, hregB[c].y}, f32x2{ss[c].x, ss[c].y}, p0);
            p1 = pkfma(f32x2{hregB[c].z, hregB[c].w}, f32x2{ss[c].z, ss[c].w}, p1);
          }
          float p = row16_sum((p0.x + p1.x) + (p0.y + p1.y));
          if (lane16 == 0) carr[g + NG] = p * wlam[g + NG];
        }
      }
      __syncthreads();

      float ah = 0.f;
      if (owner) {
        const float4* c4 = (const float4*)carr;
        float a0 = 0.f, a1 = 0.f, a2 = 0.f, a3 = 0.f;
#pragma unroll
        for (int q = 0; q < 12; ++q) {
          float4 cc = c4[q];
          a0 = fmaf(cc.x, hcol[4 * q + 0], a0);
          a1 = fmaf(cc.y, hcol[4 * q + 1], a1);
          a2 = fmaf(cc.z, hcol[4 * q + 2], a2);
          a3 = fmaf(cc.w, hcol[4 * q + 3], a3);
        }
        ah = (a0 + a2) + (a1 + a3);
        float v0 = wave_sum63(ah);
        float v1 = wave_sum63(ah * ah);
        float v2 = wave_sum63(hb * ah);
        if (lane == 63) {
          float* rb = redB[s & 1];
          rb[wv * 5 + 0] = v0; rb[wv * 5 + 1] = v1; rb[wv * 5 + 2] = v2;
        }
      }
      __syncthreads();

      if (owner) {
        const float4* rb4 = (const float4*)redB[s & 1];
        float S[5] = {0.f, 0.f, 0.f, 0.f, 0.f};
#pragma unroll
        for (int q = 0; q < 8; ++q) {
          float4 ch = rb4[q];
          S[(4 * q + 0) % 5] += ch.x;
          S[(4 * q + 1) % 5] += ch.y;
          S[(4 * q + 2) % 5] += ch.z;
          S[(4 * q + 3) % 5] += ch.w;
        }
        // xv = hb + ah : analytic stats (S[0]=sum ah, S[1]=sum ah^2, S[2]=sum hb*ah)
        float Sx  = Shb + S[0];
        float Sxx = Shb2 + 2.f * S[2] + S[1];
        float mu  = Sx * invD;
        float var = Sxx * invD - mu * mu;
        float xv  = hb + ah;
        hv = fmaxf((xv - mu) * rsqrtf(var + 1e-5f) * g_i + be_i, 0.f);
        if (s < SETI - 1) hs[tid] = hv;
      }
      if (s < SETI - 1) __syncthreads();
    }

    if (owner) out[(size_t)b * DH + tid] = hv;
  }
}

// Prologue (one launch): bf16-convert W_h AND compute
// gz[t][b][r] = fp32 W_g[r,:] . z[t][b] + b_h[r].
// grid (BB, 8): block (b, y) handles t = 6y..6y+5, Wg slice held in registers.
__global__ __launch_bounds__(PREPNT) void prep_kernel(
    const float* __restrict__ z_seq, const float* __restrict__ Wg,
    const float* __restrict__ W_h, const float* __restrict__ b_h,
    ushort_t* __restrict__ Whb, float* __restrict__ gz)
{
  __shared__ __align__(16) float zsh[DG];
  const int tid = threadIdx.x, b = blockIdx.x;
  const int g = tid >> 4, lane16 = tid & 15;

  // fold-in: fp32 -> bf16 (RTN-even) for W_h
  {
    int lid = (blockIdx.y * BB + blockIdx.x) * PREPNT + tid;
    if (lid < DH * DH) {
      unsigned u = __float_as_uint(W_h[lid]);
      unsigned r = (u + 0x7FFFu + ((u >> 16) & 1u)) >> 16;
      Whb[lid] = (ushort_t)r;
    }
  }

  float4 w[24];
#pragma unroll
  for (int p = 0; p < 8; ++p)
#pragma unroll
    for (int c = 0; c < 3; ++c)
      w[p * 3 + c] = ((const float4*)Wg)[(size_t)(8 * g + p) * (DG / 4) + lane16 + 16 * c];
  float4 bs0 = {0.f, 0.f, 0.f, 0.f}, bs1 = {0.f, 0.f, 0.f, 0.f};
  if (lane16 == 0) {
    bs0 = ((const float4*)b_h)[2 * g];
    bs1 = ((const float4*)b_h)[2 * g + 1];
  }
  for (int tt = 0; tt < 6; ++tt) {
    const int t = blockIdx.y * 6 + tt;
    __syncthreads();
    if (tid < DG / 4)
      ((float4*)zsh)[tid] = ((const float4*)(z_seq + ((size_t)t * BB + b) * DG))[tid];
    __syncthreads();
    float4 zz[3];
#pragma unroll
    for (int c = 0; c < 3; ++c) zz[c] = ((const float4*)zsh)[lane16 + 16 * c];
    float rs[8];
#pragma unroll
    for (int p = 0; p < 8; ++p) {
      f32x2 a0 = {0.f, 0.f}, a1 = {0.f, 0.f};
#pragma unroll
      for (int c = 0; c < 3; ++c) {
        a0 = pkfma(f32x2{w[p * 3 + c].x, w[p * 3 + c].y}, f32x2{zz[c].x, zz[c].y}, a0);
        a1 = pkfma(f32x2{w[p * 3 + c].z, w[p * 3 + c].w}, f32x2{zz[c].z, zz[c].w}, a1);
      }
      rs[p] = row16_sum((a0.x + a1.x) + (a0.y + a1.y));
    }
    if (lane16 == 0) {
      float* grow = gz + ((size_t)t * BB + b) * DH + 8 * g;
      ((float4*)grow)[0] = float4{rs[0] + bs0.x, rs[1] + bs0.y, rs[2] + bs0.z, rs[3] + bs0.w};
      ((float4*)grow)[1] = float4{rs[4] + bs1.x, rs[5] + bs1.y, rs[6] + bs1.z, rs[7] + bs1.w};
    }
  }
}

extern "C" void kernel_launch(void* const* d_in, const int* in_sizes, int n_in,
                              void* d_out, int out_size, void* d_ws, size_t ws_size,
                              hipStream_t stream) {
  const float* z_seq    = (const float*)d_in[0];
  const float* W_h      = (const float*)d_in[1];
  const float* W_g      = (const float*)d_in[2];
  const float* b_h      = (const float*)d_in[3];
  const float* ln_g     = (const float*)d_in[4];
  const float* ln_b     = (const float*)d_in[5];
  const float* alpha_fw = (const float*)d_in[6];
  float* out = (float*)d_out;

  const size_t nWh = (size_t)DH * DH;                              // 147456
  const size_t bf16Bytes = nWh * sizeof(ushort_t);                 // 294912
  const size_t gzBytes   = (size_t)TT * BB * DH * sizeof(float);   // 7077888

  if (ws_size >= bf16Bytes + gzBytes) {
    ushort_t* Whb = (ushort_t*)d_ws;
    float* gz = (float*)((char*)d_ws + bf16Bytes);
    prep_kernel<<<dim3(BB, 8), dim3(PREPNT), 0, stream>>>(
        z_seq, W_g, W_h, b_h, Whb, gz);
    fw_rnn_kernel<true><<<dim3(BB), dim3(NT), 0, stream>>>(
        z_seq, W_h, W_g, Whb, gz, b_h, ln_g, ln_b, alpha_fw, out);
  } else {
    fw_rnn_kernel<false><<<dim3(BB), dim3(NT), 0, stream>>>(
        z_seq, W_h, W_g, nullptr, nullptr, b_h, ln_g, ln_b, alpha_fw, out);
  }
}